// Round 1
// 206.271 us; speedup vs baseline: 1.0838x; 1.0838x over previous
//
#include <hip/hip_runtime.h>
#include <math.h>

#define D_MODEL 1024
#define NHEAD 16
#define HD 64
#define SEQ 2048
#define BATCH 2
#define MTOT (BATCH * SEQ)  // 4096

typedef __attribute__((ext_vector_type(8))) short bf16x8;
typedef __attribute__((ext_vector_type(4))) float f32x4;

__device__ __forceinline__ unsigned short f2bf(float f) {
    unsigned int u = __float_as_uint(f);
    u += 0x7FFF + ((u >> 16) & 1);  // round-to-nearest-even
    return (unsigned short)(u >> 16);
}

// packed f32x2 -> bf16x2 via HW cvt (RNE, bit-identical to f2bf for normals)
__device__ __forceinline__ unsigned int pk2bf(float a, float b) {
    unsigned int r;
    asm("v_cvt_pk_bf16_f32 %0, %1, %2" : "=v"(r) : "v"(a), "v"(b));
    return r;
}

// async global->LDS, 16B per lane. lds must be the wave-uniform chunk base:
// HW writes lane's 16B to base + lane*16 (guide §5 caveat).
__device__ __forceinline__ void async16(unsigned short* lds, const unsigned short* g) {
    __builtin_amdgcn_global_load_lds(
        (const __attribute__((address_space(1))) unsigned int*)g,
        (__attribute__((address_space(3))) unsigned int*)lds, 16, 0, 0);
}

// ---------------------------------------------------------------------------
// Fused prep: blocks [0,4096) convert x fp32->bf16; blocks [4096,8192)
// transpose the 4 weights W[k][n] fp32 -> Wt[n][k] bf16.
// ---------------------------------------------------------------------------
__global__ __launch_bounds__(256) void prep(const float* __restrict__ x,
                                            unsigned short* __restrict__ xb,
                                            const float* __restrict__ W0,
                                            const float* __restrict__ W1,
                                            const float* __restrict__ W2,
                                            const float* __restrict__ W3,
                                            unsigned short* __restrict__ Wt) {
    const int bid = blockIdx.x;
    const int tid = threadIdx.x;
    if (bid < 4096) {
        const int i = (bid * 256 + tid) * 4;
        float4 v = *(const float4*)(x + i);
        uint2 pk;
        pk.x = pk2bf(v.x, v.y);
        pk.y = pk2bf(v.z, v.w);
        *(uint2*)(xb + i) = pk;
    } else {
        __shared__ float T[32][33];
        const int t = bid - 4096;
        const int z = t >> 10, rem = t & 1023;
        const int n0 = (rem & 31) * 32, k0 = (rem >> 5) * 32;
        const float* W = (z == 0) ? W0 : (z == 1) ? W1 : (z == 2) ? W2 : W3;
        unsigned short* out = Wt + (size_t)z * D_MODEL * D_MODEL;
        const int tx = tid & 31, ty = tid >> 5;
#pragma unroll
        for (int i = 0; i < 4; ++i)
            T[ty + 8 * i][tx] = W[(size_t)(k0 + ty + 8 * i) * D_MODEL + n0 + tx];
        __syncthreads();
#pragma unroll
        for (int i = 0; i < 4; ++i)
            out[(size_t)(n0 + ty + 8 * i) * D_MODEL + k0 + tx] = f2bf(T[tx][ty + 8 * i]);
    }
}

// ---------------------------------------------------------------------------
// bf16 MFMA GEMM, global_load_lds staging (width=16, unpadded LDS).
// 128x128 tile / block, BK=64, 256 threads = 4 waves (2x2), each wave 64x64.
// MODE 0: z selects Wq/Wk/Wv; writes Q (pre-scaled by 0.125*log2e), K ->
//         [B,H,N,64] and V -> V^T [B,H,64,N]; ALL epilogues LDS-staged with
//         fully-coalesced 16B stores.
// MODE 1: fp32 row-major output.
// ---------------------------------------------------------------------------
template <int MODE>
__global__ __launch_bounds__(256) void gemm_mfma(const unsigned short* __restrict__ A,
                                                 const unsigned short* __restrict__ Wt,
                                                 unsigned short* __restrict__ q,
                                                 unsigned short* __restrict__ k,
                                                 unsigned short* __restrict__ vt,
                                                 float* __restrict__ outf) {
    __shared__ unsigned short SM[16384];  // As = SM[0:8192), Bs = SM[8192:16384)
    const int tid = threadIdx.x;
    const int z = blockIdx.z;
    const unsigned short* B = Wt + (size_t)z * D_MODEL * D_MODEL;
    const int m0 = blockIdx.y * 128, n0 = blockIdx.x * 128;
    const int wave = tid >> 6, lane = tid & 63;
    const int quad = lane >> 4, l16 = lane & 15;
    const int wm = wave & 1, wn = wave >> 1;

    f32x4 acc[4][4];
#pragma unroll
    for (int mt = 0; mt < 4; ++mt)
#pragma unroll
        for (int nt = 0; nt < 4; ++nt)
            acc[mt][nt] = (f32x4){0.f, 0.f, 0.f, 0.f};

    for (int k0 = 0; k0 < D_MODEL; k0 += 64) {
        __syncthreads();  // previous iteration's reads done
#pragma unroll
        for (int i = 0; i < 4; ++i) {
            const int c = i * 256 + tid;
            const int r = c >> 3, cc = (c & 7) * 8;
            const int cbase = i * 256 + wave * 64;  // wave-uniform chunk base
            async16(SM + cbase * 8, A + (size_t)(m0 + r) * D_MODEL + k0 + cc);
            async16(SM + 8192 + cbase * 8, B + (size_t)(n0 + r) * D_MODEL + k0 + cc);
        }
        __syncthreads();  // drains vmcnt per barrier semantics
#pragma unroll
        for (int ks = 0; ks < 2; ++ks) {
            bf16x8 af[4], bfr[4];
#pragma unroll
            for (int mt = 0; mt < 4; ++mt)
                af[mt] = *(const bf16x8*)&SM[(wm * 64 + mt * 16 + l16) * 64 + ks * 32 + quad * 8];
#pragma unroll
            for (int nt = 0; nt < 4; ++nt)
                bfr[nt] = *(const bf16x8*)&SM[8192 + (wn * 64 + nt * 16 + l16) * 64 + ks * 32 + quad * 8];
#pragma unroll
            for (int mt = 0; mt < 4; ++mt)
#pragma unroll
                for (int nt = 0; nt < 4; ++nt)
                    acc[mt][nt] = __builtin_amdgcn_mfma_f32_16x16x32_bf16(
                        af[mt], bfr[nt], acc[mt][nt], 0, 0, 0);
        }
    }

    if (MODE == 1) {
#pragma unroll
        for (int mt = 0; mt < 4; ++mt)
#pragma unroll
            for (int nt = 0; nt < 4; ++nt)
#pragma unroll
                for (int reg = 0; reg < 4; ++reg) {
                    const int m = m0 + wm * 64 + mt * 16 + quad * 4 + reg;
                    const int n = n0 + wn * 64 + nt * 16 + l16;
                    outf[(size_t)m * D_MODEL + n] = acc[mt][nt][reg];
                }
    } else if (z < 2) {
        // Q/K epilogue: stage [tok][d] in LDS (2 heads side by side, row
        // stride 128), then fully-coalesced uint4 stores. 2 passes (wm).
        // Q gets softmax scale folded in (exp2 domain): 0.125 * log2(e).
        const float qsc = (z == 0) ? 0.18033688011112042f : 1.0f;
        unsigned short* dst = (z == 0) ? q : k;
        const int bb = m0 >> 11;
        const int tok0 = m0 & (SEQ - 1);
        const int h0 = n0 >> 6;  // 2 heads per 128-col tile
#pragma unroll
        for (int pass = 0; pass < 2; ++pass) {
            __syncthreads();  // SM free (K-loop or previous pass done)
            if (wm == pass) {
#pragma unroll
                for (int mt = 0; mt < 4; ++mt)
#pragma unroll
                    for (int nt = 0; nt < 4; ++nt)
#pragma unroll
                        for (int reg = 0; reg < 4; ++reg) {
                            const int r = mt * 16 + quad * 4 + reg;
                            const int cc = wn * 64 + nt * 16 + l16;
                            SM[r * 128 + cc] = f2bf(acc[mt][nt][reg] * qsc);
                        }
            }
            __syncthreads();
#pragma unroll
            for (int it = 0; it < 4; ++it) {
                const int cix = it * 256 + tid;
                const int r = cix >> 4, g = cix & 15;
                const int hh = g >> 3, d8 = g & 7;
                uint4 val = *(const uint4*)&SM[r * 128 + g * 8];
                *(uint4*)(dst + (((size_t)bb * NHEAD + h0 + hh) * SEQ +
                                 tok0 + pass * 64 + r) * HD + d8 * 8) = val;
            }
        }
    } else {
        // V^T epilogue: stage [d][m] in LDS (pad 136), then coalesced stores.
        const int bb = m0 >> 11, tok0 = m0 & (SEQ - 1);
#pragma unroll
        for (int pass = 0; pass < 2; ++pass) {
            __syncthreads();  // SM free (K-loop or previous pass done)
            if (wn == pass) {
#pragma unroll
                for (int mt = 0; mt < 4; ++mt)
#pragma unroll
                    for (int nt = 0; nt < 4; ++nt) {
                        const int d = nt * 16 + l16;
                        const int m = wm * 64 + mt * 16 + quad * 4;
                        uint2 w;
                        w.x = pk2bf(acc[mt][nt][0], acc[mt][nt][1]);
                        w.y = pk2bf(acc[mt][nt][2], acc[mt][nt][3]);
                        *(uint2*)&SM[d * 136 + m] = w;
                    }
            }
            __syncthreads();
            const int h = (n0 >> 6) + pass;
#pragma unroll
            for (int it = 0; it < 4; ++it) {
                const int c = it * 256 + tid;
                const int d = c >> 4, mc = (c & 15) * 8;
                uint4 val = *(const uint4*)&SM[d * 136 + mc];
                *(uint4*)(vt + (((size_t)bb * NHEAD + h) * HD + d) * SEQ + tok0 + mc) = val;
            }
        }
    }
}

// ---------------------------------------------------------------------------
// MFMA flash attention (causal), PAIRED q-tiles + 4-way kt-SPLIT.
// Grid (NHEAD, 16, BATCH), block 256 = 4 waves. Each block handles q-tiles
// {31-y, y}: (p0+1)+(p1+1) = 33 kt-iterations ALWAYS -> perfectly uniform
// work, no causal tail (old version: 1024 imbalanced blocks, occupancy 9.5%).
// Per tile, wave w accumulates O,l over kt ∈ {w, w+4, ...} (fixed-shift
// additive softmax -> order-free), ~8-9 serial iterations max per wave.
// No barriers in the kt loop; cross-wave combine is a 2-round LDS tree
// (regions overlaid on the Ps scratch; barriers only between phases).
// Ps is XOR-swizzled unpadded [64][64] per wave (R9-verified formulas).
// bf16 packing via v_cvt_pk_bf16_f32 (1 op / 2 vals vs ~7 manual).
// ---------------------------------------------------------------------------
__global__ __launch_bounds__(256, 2) void attn_mfma(const unsigned short* __restrict__ Q,
                                                    const unsigned short* __restrict__ K,
                                                    const unsigned short* __restrict__ VT,
                                                    unsigned short* __restrict__ ctx) {
    // Union LDS (35.3 KB):
    //   loop phase:    Ps = ushort[4][4096] (8 KB per wave), floats [0,8192)
    //   combine phase: R0 = floats [0,4352)  = 64x68 padded O partial
    //                  R1 = floats [4352,8704)
    //                  Ls = floats [8704,8832) = 2x64 row-sum partials
    __shared__ float CMB[8832];
    const int tid = threadIdx.x;
    const int wave = tid >> 6, lane = tid & 63;
    const int quad = lane >> 4, l16 = lane & 15;
    const int h = blockIdx.x, b = blockIdx.z;
    const int y = blockIdx.y;
    const unsigned short* Qp = Q + ((size_t)b * NHEAD + h) * SEQ * HD;
    const unsigned short* Kp = K + ((size_t)b * NHEAD + h) * SEQ * HD;
    const unsigned short* Vp = VT + ((size_t)b * NHEAD + h) * HD * SEQ;
    unsigned short* Pw = (unsigned short*)CMB + wave * 4096;
    const int sw8 = l16 & 7;  // swizzle key (row & 7)

#pragma unroll 1
    for (int half = 0; half < 2; ++half) {
        const int p = half ? y : (31 - y);  // heavy tile first
        const int row0 = p * 64;
        if (half) __syncthreads();  // previous combine's LDS reads done

        bf16x8 bQ[4][2];  // Q as B-operand: [q-frag][ks]
#pragma unroll
        for (int f = 0; f < 4; ++f)
#pragma unroll
            for (int ks = 0; ks < 2; ++ks)
                bQ[f][ks] = *(const bf16x8*)(Qp +
                    (size_t)(row0 + f * 16 + l16) * HD + ks * 32 + quad * 8);

        f32x4 o[4][4];    // O^T accumulators: [d-tile][q-frag]
        float ps[4] = {0.f, 0.f, 0.f, 0.f};
#pragma unroll
        for (int nt = 0; nt < 4; ++nt)
#pragma unroll
            for (int f = 0; f < 4; ++f)
                o[nt][f] = (f32x4){0.f, 0.f, 0.f, 0.f};

        for (int kt = wave; kt <= p; kt += 4) {
            // ---- K/V fragments (direct global; no loop barriers, compiler
            //      free to pipeline across iterations) ----
            bf16x8 aK[4][2], aV[4][2];
#pragma unroll
            for (int mt = 0; mt < 4; ++mt)
#pragma unroll
                for (int ks = 0; ks < 2; ++ks)
                    aK[mt][ks] = *(const bf16x8*)(Kp +
                        (size_t)(kt * 64 + mt * 16 + l16) * HD + ks * 32 + quad * 8);
#pragma unroll
            for (int nt = 0; nt < 4; ++nt)
#pragma unroll
                for (int ks = 0; ks < 2; ++ks)
                    aV[nt][ks] = *(const bf16x8*)(Vp +
                        (size_t)(nt * 16 + l16) * SEQ + kt * 64 + ks * 32 + quad * 8);

            // ---- S^T = K Q^T ----
            f32x4 sT[4][4];
            __builtin_amdgcn_s_setprio(1);
#pragma unroll
            for (int mt = 0; mt < 4; ++mt)
#pragma unroll
                for (int f = 0; f < 4; ++f) {
                    sT[mt][f] = __builtin_amdgcn_mfma_f32_16x16x32_bf16(
                        aK[mt][0], bQ[f][0], (f32x4){0.f, 0.f, 0.f, 0.f}, 0, 0, 0);
                    sT[mt][f] = __builtin_amdgcn_mfma_f32_16x16x32_bf16(
                        aK[mt][1], bQ[f][1], sT[mt][f], 0, 0, 0);
                }
            __builtin_amdgcn_s_setprio(0);

            // ---- exp2 + causal mask (diag tile only) + swizzled P write ----
            const bool diag = (kt == p);
#pragma unroll
            for (int mt = 0; mt < 4; ++mt)
#pragma unroll
                for (int f = 0; f < 4; ++f) {
                    float pv[4];
#pragma unroll
                    for (int reg = 0; reg < 4; ++reg)
                        pv[reg] = exp2f(sT[mt][f][reg]);
                    if (diag) {
                        const int kb = kt * 64 + mt * 16 + quad * 4;
                        const int qg = row0 + f * 16 + l16;
#pragma unroll
                        for (int reg = 0; reg < 4; ++reg)
                            pv[reg] = (kb + reg > qg) ? 0.f : pv[reg];
                    }
                    ps[f] += (pv[0] + pv[1]) + (pv[2] + pv[3]);
                    uint2 w;
                    w.x = pk2bf(pv[0], pv[1]);
                    w.y = pk2bf(pv[2], pv[3]);
                    const int gph = ((mt * 2 + (quad >> 1)) ^ sw8);
                    *(uint2*)&Pw[(f * 16 + l16) * 64 + gph * 8 + (quad & 1) * 4] = w;
                }

            // ---- P back in B-layout (wave-private; same-wave DS order) ----
            bf16x8 bP[4][2];
#pragma unroll
            for (int f = 0; f < 4; ++f)
#pragma unroll
                for (int ks = 0; ks < 2; ++ks)
                    bP[f][ks] = *(const bf16x8*)&Pw[(f * 16 + l16) * 64 +
                                                    ((ks * 4 + quad) ^ sw8) * 8];

            // ---- O^T += V^T P^T ----
            __builtin_amdgcn_s_setprio(1);
#pragma unroll
            for (int nt = 0; nt < 4; ++nt)
#pragma unroll
                for (int f = 0; f < 4; ++f) {
                    o[nt][f] = __builtin_amdgcn_mfma_f32_16x16x32_bf16(
                        aV[nt][0], bP[f][0], o[nt][f], 0, 0, 0);
                    o[nt][f] = __builtin_amdgcn_mfma_f32_16x16x32_bf16(
                        aV[nt][1], bP[f][1], o[nt][f], 0, 0, 0);
                }
            __builtin_amdgcn_s_setprio(0);
        }

        // ---- reduce ps across quads (q-row lives in l16; partials in quads) --
#pragma unroll
        for (int f = 0; f < 4; ++f) {
            ps[f] += __shfl_xor(ps[f], 16);
            ps[f] += __shfl_xor(ps[f], 32);
        }

        // ---- cross-wave tree combine: {2,3} -> {0,1} -> 0 ----
        __syncthreads();  // all waves done with Pw (regions overlay it)
        if (wave >= 2) {
            float* Rg = CMB + (wave - 2) * 4352;
#pragma unroll
            for (int nt = 0; nt < 4; ++nt)
#pragma unroll
                for (int f = 0; f < 4; ++f)
                    *(f32x4*)&Rg[(f * 16 + l16) * 68 + nt * 16 + quad * 4] = o[nt][f];
            if (quad == 0)
#pragma unroll
                for (int f = 0; f < 4; ++f)
                    CMB[8704 + (wave - 2) * 64 + f * 16 + l16] = ps[f];
        }
        __syncthreads();
        if (wave < 2) {
            float* Rg = CMB + wave * 4352;
#pragma unroll
            for (int nt = 0; nt < 4; ++nt)
#pragma unroll
                for (int f = 0; f < 4; ++f)
                    o[nt][f] += *(const f32x4*)&Rg[(f * 16 + l16) * 68 + nt * 16 + quad * 4];
#pragma unroll
            for (int f = 0; f < 4; ++f)
                ps[f] += CMB[8704 + wave * 64 + f * 16 + l16];
        }
        __syncthreads();
        if (wave == 1) {
#pragma unroll
            for (int nt = 0; nt < 4; ++nt)
#pragma unroll
                for (int f = 0; f < 4; ++f)
                    *(f32x4*)&CMB[(f * 16 + l16) * 68 + nt * 16 + quad * 4] = o[nt][f];
            if (quad == 0)
#pragma unroll
                for (int f = 0; f < 4; ++f)
                    CMB[8704 + f * 16 + l16] = ps[f];
        }
        __syncthreads();
        if (wave == 0) {
#pragma unroll
            for (int nt = 0; nt < 4; ++nt)
#pragma unroll
                for (int f = 0; f < 4; ++f)
                    o[nt][f] += *(const f32x4*)&CMB[(f * 16 + l16) * 68 + nt * 16 + quad * 4];
            float inv[4];
#pragma unroll
            for (int f = 0; f < 4; ++f)
                inv[f] = 1.f / (ps[f] + CMB[8704 + f * 16 + l16]);
#pragma unroll
            for (int nt = 0; nt < 4; ++nt)
#pragma unroll
                for (int f = 0; f < 4; ++f) {
                    const int tok = row0 + f * 16 + l16;
                    const int col = h * HD + nt * 16 + quad * 4;
                    uint2 w;
                    w.x = pk2bf(o[nt][f][0] * inv[f], o[nt][f][1] * inv[f]);
                    w.y = pk2bf(o[nt][f][2] * inv[f], o[nt][f][3] * inv[f]);
                    *(uint2*)(ctx + ((size_t)b * SEQ + tok) * D_MODEL + col) = w;
                }
        }
    }
}

extern "C" void kernel_launch(void* const* d_in, const int* in_sizes, int n_in,
                              void* d_out, int out_size, void* d_ws, size_t ws_size,
                              hipStream_t stream) {
    const float* x  = (const float*)d_in[0];
    const float* Wq = (const float*)d_in[1];
    const float* Wk = (const float*)d_in[2];
    const float* Wv = (const float*)d_in[3];
    const float* Wo = (const float*)d_in[4];
    float* out = (float*)d_out;

    unsigned short* ws = (unsigned short*)d_ws;
    const size_t T = (size_t)MTOT * D_MODEL;  // 4,194,304 elements
    unsigned short* xb  = ws;                 // [4096,1024] bf16
    unsigned short* Wt  = ws + T;             // 4 x [1024,1024] bf16 (W^T)
    unsigned short* q   = ws + 2 * T;         // [B,H,N,64]  (pre-scaled)
    unsigned short* k   = ws + 3 * T;         // [B,H,N,64]
    unsigned short* vt  = ws + 4 * T;         // [B,H,64,N]
    unsigned short* ctx = ws + 5 * T;         // [4096,1024]

    prep<<<dim3(8192), dim3(256), 0, stream>>>(x, xb, Wq, Wk, Wv, Wo, Wt);

    gemm_mfma<0><<<dim3(8, 32, 3), dim3(256), 0, stream>>>(xb, Wt, q, k, vt, nullptr);

    attn_mfma<<<dim3(NHEAD, 16, BATCH), dim3(256), 0, stream>>>(q, k, vt, ctx);

    gemm_mfma<1><<<dim3(8, 32, 1), dim3(256), 0, stream>>>(ctx, Wt + 3 * (size_t)D_MODEL * D_MODEL,
                                                           nullptr, nullptr, nullptr, out);
}

// Round 2
// 188.951 us; speedup vs baseline: 1.1832x; 1.0917x over previous
//
#include <hip/hip_runtime.h>
#include <math.h>

#define D_MODEL 1024
#define NHEAD 16
#define HD 64
#define SEQ 2048
#define BATCH 2
#define MTOT (BATCH * SEQ)  // 4096

typedef __attribute__((ext_vector_type(8))) short bf16x8;
typedef __attribute__((ext_vector_type(4))) float f32x4;

__device__ __forceinline__ unsigned short f2bf(float f) {
    unsigned int u = __float_as_uint(f);
    u += 0x7FFF + ((u >> 16) & 1);  // round-to-nearest-even
    return (unsigned short)(u >> 16);
}

// packed f32x2 -> bf16x2 via HW cvt (RNE, bit-identical to f2bf for normals)
__device__ __forceinline__ unsigned int pk2bf(float a, float b) {
    unsigned int r;
    asm("v_cvt_pk_bf16_f32 %0, %1, %2" : "=v"(r) : "v"(a), "v"(b));
    return r;
}

// async global->LDS, 16B per lane. lds must be the wave-uniform chunk base:
// HW writes lane's 16B to base + lane*16 (guide §5 caveat).
__device__ __forceinline__ void async16(unsigned short* lds, const unsigned short* g) {
    __builtin_amdgcn_global_load_lds(
        (const __attribute__((address_space(1))) unsigned int*)g,
        (__attribute__((address_space(3))) unsigned int*)lds, 16, 0, 0);
}

// raw barrier with compiler memory fence (no vmcnt drain, unlike __syncthreads)
__device__ __forceinline__ void BAR() {
    asm volatile("" ::: "memory");
    __builtin_amdgcn_s_barrier();
    asm volatile("" ::: "memory");
}

// ---------------------------------------------------------------------------
// Fused prep: blocks [0,4096) convert x fp32->bf16; blocks [4096,8192)
// transpose the 4 weights W[k][n] fp32 -> Wt[n][k] bf16.
// ---------------------------------------------------------------------------
__global__ __launch_bounds__(256) void prep(const float* __restrict__ x,
                                            unsigned short* __restrict__ xb,
                                            const float* __restrict__ W0,
                                            const float* __restrict__ W1,
                                            const float* __restrict__ W2,
                                            const float* __restrict__ W3,
                                            unsigned short* __restrict__ Wt) {
    const int bid = blockIdx.x;
    const int tid = threadIdx.x;
    if (bid < 4096) {
        const int i = (bid * 256 + tid) * 4;
        float4 v = *(const float4*)(x + i);
        uint2 pk;
        pk.x = pk2bf(v.x, v.y);
        pk.y = pk2bf(v.z, v.w);
        *(uint2*)(xb + i) = pk;
    } else {
        __shared__ float T[32][33];
        const int t = bid - 4096;
        const int z = t >> 10, rem = t & 1023;
        const int n0 = (rem & 31) * 32, k0 = (rem >> 5) * 32;
        const float* W = (z == 0) ? W0 : (z == 1) ? W1 : (z == 2) ? W2 : W3;
        unsigned short* out = Wt + (size_t)z * D_MODEL * D_MODEL;
        const int tx = tid & 31, ty = tid >> 5;
#pragma unroll
        for (int i = 0; i < 4; ++i)
            T[ty + 8 * i][tx] = W[(size_t)(k0 + ty + 8 * i) * D_MODEL + n0 + tx];
        __syncthreads();
#pragma unroll
        for (int i = 0; i < 4; ++i)
            out[(size_t)(n0 + ty + 8 * i) * D_MODEL + k0 + tx] = f2bf(T[tx][ty + 8 * i]);
    }
}

// ---------------------------------------------------------------------------
// Fused QKV GEMM: 256x256 tile, 8-phase schedule (T2+T3+T4+T5 per guide §5.5).
// M=4096 (tokens), N=3072 (Wq|Wk|Wv), K=1024. Grid 192 blocks x 512 thr
// (8 waves, 2M x 4N, per-wave 128x64 output). BK=64 per K-tile, staged as
// 4 half-tiles {A,B} x {K-half}; double-buffered 128 KB LDS; counted
// vmcnt(4) at phases 2/4 only (never drained in-loop); setprio around MFMA.
// LDS swizzle: chunk c of row r at slot r*4 + (c ^ ((r+(r>>2))&3)) ->
// 2-way (free) banks on ds_read_b128; implemented as pre-swizzled GLOBAL
// source + swizzled read (global_load_lds dest stays linear, rule #21).
// Epilogues: Q (x0.125*log2e) / K -> [B,H,N,64]; V -> V^T [B,H,64,N];
// LDS-staged, fully-coalesced uint4 stores.
// ---------------------------------------------------------------------------
__global__ __launch_bounds__(512, 2) void qkv_mfma(const unsigned short* __restrict__ A,
                                                   const unsigned short* __restrict__ Wt,
                                                   unsigned short* __restrict__ q,
                                                   unsigned short* __restrict__ k,
                                                   unsigned short* __restrict__ vt) {
    __shared__ unsigned short SM[65536];  // 128 KB: [dbuf][op][ks][1024 slots x 16B]
    const int tid = threadIdx.x;
    const int wave = tid >> 6, lane = tid & 63;
    const int quad = lane >> 4, l16 = lane & 15;
    const int wm = wave >> 2, wn = wave & 3;

    // XCD-chunked block swizzle (192 % 8 == 0 -> bijective simple form)
    const int bid = blockIdx.x;
    const int swz = (bid & 7) * 24 + (bid >> 3);
    const int by = swz / 12, bx = swz % 12;
    const int m0 = by * 256;
    const int z = bx >> 2, c0 = (bx & 3) * 256;  // weight id, col base within z
    const unsigned short* Bz = Wt + (size_t)z * D_MODEL * D_MODEL;

    // ---- staging descriptors: thread covers slots {tid, 512+tid} of each
    //      16KB half-tile region; source chunk pre-swizzled ----
    const unsigned short* aptr[2];
    const unsigned short* bptr[2];
    int ldsoff[2];  // ushort units
#pragma unroll
    for (int j = 0; j < 2; ++j) {
        const int s = j * 512 + tid;
        const int r = s >> 2;
        const int cg = (s & 3) ^ ((r + (r >> 2)) & 3);
        aptr[j] = A + (size_t)(m0 + r) * D_MODEL + cg * 8;
        bptr[j] = Bz + (size_t)(c0 + r) * D_MODEL + cg * 8;
        ldsoff[j] = (j * 512 + wave * 64) * 8;
    }

    // ---- fragment read offsets (swizzled; key matches staging) ----
    const int key = (l16 + (l16 >> 2)) & 3;
    const int chunk = quad ^ key;
    int aoff[8], boff[4];  // ushort units within [ks] region / [op] region
#pragma unroll
    for (int mt = 0; mt < 8; ++mt)
        aoff[mt] = ((wm * 128 + mt * 16 + l16) * 4 + chunk) * 8;
#pragma unroll
    for (int nt = 0; nt < 4; ++nt)
        boff[nt] = 16384 + ((wn * 64 + nt * 16 + l16) * 4 + chunk) * 8;

    f32x4 acc[8][4];
#pragma unroll
    for (int mt = 0; mt < 8; ++mt)
#pragma unroll
        for (int nt = 0; nt < 4; ++nt)
            acc[mt][nt] = (f32x4){0.f, 0.f, 0.f, 0.f};

    auto stage = [&](int d, int op, int ks, int T) {
        const int base = d * 32768 + op * 16384 + ks * 8192;
#pragma unroll
        for (int j = 0; j < 2; ++j)
            async16(SM + base + ldsoff[j],
                    (op ? bptr[j] : aptr[j]) + T * 64 + ks * 32);
    };
    auto dsA = [&](bf16x8* af, int mh, int d, int ks) {
        const int base = d * 32768 + ks * 8192;
#pragma unroll
        for (int i = 0; i < 4; ++i)
            af[i] = *(const bf16x8*)&SM[base + aoff[mh * 4 + i]];
    };
    auto dsB = [&](bf16x8* bf, int d, int ks) {
        const int base = d * 32768 + ks * 8192;
#pragma unroll
        for (int i = 0; i < 4; ++i)
            bf[i] = *(const bf16x8*)&SM[base + boff[i]];
    };
    auto mfma16 = [&](bf16x8* af, bf16x8* bf, int mh) {
        __builtin_amdgcn_s_setprio(1);
#pragma unroll
        for (int i = 0; i < 4; ++i)
#pragma unroll
            for (int nt = 0; nt < 4; ++nt)
                acc[mh * 4 + i][nt] = __builtin_amdgcn_mfma_f32_16x16x32_bf16(
                    af[i], bf[nt], acc[mh * 4 + i][nt], 0, 0, 0);
        __builtin_amdgcn_s_setprio(0);
    };

    // ---- prologue: stage tile 0 (A0,B0,A1,B1), retire A0+B0, sync ----
    stage(0, 0, 0, 0);
    stage(0, 1, 0, 0);
    stage(0, 0, 1, 0);
    stage(0, 1, 1, 0);
    asm volatile("s_waitcnt vmcnt(4)" ::: "memory");
    BAR();

    const int NT = D_MODEL / 64;  // 16
    for (int T = 0; T < NT; ++T) {
        const int d = T & 1, dn = d ^ 1;
        const bool nx = (T + 1 < NT);
        bf16x8 af[4], bf[4];
        // ph1: quadrant (mh=0, ks=0); issue A-half0(T+1)
        if (nx) stage(dn, 0, 0, T + 1);
        dsA(af, 0, d, 0);
        dsB(bf, d, 0);
        mfma16(af, bf, 0);
        BAR();
        // ph2: (mh=1, ks=0) reusing bf; issue B-half0(T+1); retire A1,B1(T)
        if (nx) stage(dn, 1, 0, T + 1);
        dsA(af, 1, d, 0);
        mfma16(af, bf, 1);
        if (nx) asm volatile("s_waitcnt vmcnt(4)" ::: "memory");
        else    asm volatile("s_waitcnt vmcnt(0)" ::: "memory");
        BAR();
        // ph3: (mh=0, ks=1); issue A-half1(T+1)
        if (nx) stage(dn, 0, 1, T + 1);
        dsA(af, 0, d, 1);
        dsB(bf, d, 1);
        mfma16(af, bf, 0);
        BAR();
        // ph4: (mh=1, ks=1); issue B-half1(T+1); retire A0,B0(T+1)
        if (nx) stage(dn, 1, 1, T + 1);
        dsA(af, 1, d, 1);
        mfma16(af, bf, 1);
        if (nx) asm volatile("s_waitcnt vmcnt(4)" ::: "memory");
        else    asm volatile("s_waitcnt vmcnt(0)" ::: "memory");
        BAR();
    }

    // ---- epilogues (LDS re-staged, coalesced 16B stores) ----
    __syncthreads();
    const int bb = m0 >> 11, tok0 = m0 & (SEQ - 1), h0 = c0 >> 6;  // 4 heads/block
    if (z < 2) {
        const float qsc = (z == 0) ? 0.18033688011112042f : 1.0f;  // 0.125*log2(e)
        unsigned short* dst = (z == 0) ? q : k;
#pragma unroll
        for (int pass = 0; pass < 2; ++pass) {
            if (pass) __syncthreads();
            if (wm == pass) {
#pragma unroll
                for (int mt = 0; mt < 8; ++mt)
#pragma unroll
                    for (int nt = 0; nt < 4; ++nt)
#pragma unroll
                        for (int reg = 0; reg < 4; ++reg) {
                            const int rr = mt * 16 + quad * 4 + reg;
                            const int cc = wn * 64 + nt * 16 + l16;
                            SM[rr * 264 + cc] = f2bf(acc[mt][nt][reg] * qsc);
                        }
            }
            __syncthreads();
#pragma unroll
            for (int it = 0; it < 8; ++it) {
                const int g = it * 512 + tid;
                const int r = g >> 5, gg = g & 31;
                uint4 val = *(const uint4*)&SM[r * 264 + gg * 8];
                *(uint4*)(dst + (((size_t)bb * NHEAD + h0 + (gg >> 3)) * SEQ +
                                 tok0 + pass * 128 + r) * HD + (gg & 7) * 8) = val;
            }
        }
    } else {
        // V^T: stage [d 0..255][tok 0..127] (pad 136), coalesced stores.
#pragma unroll
        for (int pass = 0; pass < 2; ++pass) {
            if (pass) __syncthreads();
            if (wm == pass) {
#pragma unroll
                for (int mt = 0; mt < 8; ++mt)
#pragma unroll
                    for (int nt = 0; nt < 4; ++nt) {
                        const int dd = wn * 64 + nt * 16 + l16;
                        const int m = mt * 16 + quad * 4;
                        uint2 w;
                        w.x = pk2bf(acc[mt][nt][0], acc[mt][nt][1]);
                        w.y = pk2bf(acc[mt][nt][2], acc[mt][nt][3]);
                        *(uint2*)&SM[dd * 136 + m] = w;
                    }
            }
            __syncthreads();
#pragma unroll
            for (int it = 0; it < 8; ++it) {
                const int g = it * 512 + tid;
                const int dd = g >> 4, tg = (g & 15) * 8;
                uint4 val = *(const uint4*)&SM[dd * 136 + tg];
                *(uint4*)(vt + (((size_t)bb * NHEAD + h0 + (dd >> 6)) * HD + (dd & 63)) * SEQ +
                          tok0 + pass * 128 + tg) = val;
            }
        }
    }
}

// ---------------------------------------------------------------------------
// bf16 MFMA GEMM (output projection only): 128x128 tile, BK=64, 4 waves,
// global_load_lds staging, fp32 row-major output.
// ---------------------------------------------------------------------------
__global__ __launch_bounds__(256) void gemm_out(const unsigned short* __restrict__ A,
                                                const unsigned short* __restrict__ Bw,
                                                float* __restrict__ outf) {
    __shared__ unsigned short SM[16384];  // As = SM[0:8192), Bs = SM[8192:16384)
    const int tid = threadIdx.x;
    const int m0 = blockIdx.y * 128, n0 = blockIdx.x * 128;
    const int wave = tid >> 6, lane = tid & 63;
    const int quad = lane >> 4, l16 = lane & 15;
    const int wm = wave & 1, wn = wave >> 1;

    f32x4 acc[4][4];
#pragma unroll
    for (int mt = 0; mt < 4; ++mt)
#pragma unroll
        for (int nt = 0; nt < 4; ++nt)
            acc[mt][nt] = (f32x4){0.f, 0.f, 0.f, 0.f};

    for (int k0 = 0; k0 < D_MODEL; k0 += 64) {
        __syncthreads();
#pragma unroll
        for (int i = 0; i < 4; ++i) {
            const int c = i * 256 + tid;
            const int r = c >> 3, cc = (c & 7) * 8;
            const int cbase = i * 256 + wave * 64;  // wave-uniform chunk base
            async16(SM + cbase * 8, A + (size_t)(m0 + r) * D_MODEL + k0 + cc);
            async16(SM + 8192 + cbase * 8, Bw + (size_t)(n0 + r) * D_MODEL + k0 + cc);
        }
        __syncthreads();
#pragma unroll
        for (int ks = 0; ks < 2; ++ks) {
            bf16x8 af[4], bfr[4];
#pragma unroll
            for (int mt = 0; mt < 4; ++mt)
                af[mt] = *(const bf16x8*)&SM[(wm * 64 + mt * 16 + l16) * 64 + ks * 32 + quad * 8];
#pragma unroll
            for (int nt = 0; nt < 4; ++nt)
                bfr[nt] = *(const bf16x8*)&SM[8192 + (wn * 64 + nt * 16 + l16) * 64 + ks * 32 + quad * 8];
#pragma unroll
            for (int mt = 0; mt < 4; ++mt)
#pragma unroll
                for (int nt = 0; nt < 4; ++nt)
                    acc[mt][nt] = __builtin_amdgcn_mfma_f32_16x16x32_bf16(
                        af[mt], bfr[nt], acc[mt][nt], 0, 0, 0);
        }
    }

#pragma unroll
    for (int mt = 0; mt < 4; ++mt)
#pragma unroll
        for (int nt = 0; nt < 4; ++nt)
#pragma unroll
            for (int reg = 0; reg < 4; ++reg) {
                const int m = m0 + wm * 64 + mt * 16 + quad * 4 + reg;
                const int n = n0 + wn * 64 + nt * 16 + l16;
                outf[(size_t)m * D_MODEL + n] = acc[mt][nt][reg];
            }
}

// ---------------------------------------------------------------------------
// MFMA flash attention (causal), PAIRED q-tiles + 4-way kt-SPLIT.
// Grid (NHEAD, 16, BATCH), block 256 = 4 waves. Each block handles q-tiles
// {31-y, y}: 33 kt-iterations always -> uniform work. No barriers in the
// kt loop; cross-wave combine is a 2-round LDS tree.
// ---------------------------------------------------------------------------
__global__ __launch_bounds__(256, 2) void attn_mfma(const unsigned short* __restrict__ Q,
                                                    const unsigned short* __restrict__ K,
                                                    const unsigned short* __restrict__ VT,
                                                    unsigned short* __restrict__ ctx) {
    // Union LDS (35.3 KB): loop: Ps = ushort[4][4096]; combine: R0/R1/Ls.
    __shared__ float CMB[8832];
    const int tid = threadIdx.x;
    const int wave = tid >> 6, lane = tid & 63;
    const int quad = lane >> 4, l16 = lane & 15;
    const int h = blockIdx.x, b = blockIdx.z;
    const int y = blockIdx.y;
    const unsigned short* Qp = Q + ((size_t)b * NHEAD + h) * SEQ * HD;
    const unsigned short* Kp = K + ((size_t)b * NHEAD + h) * SEQ * HD;
    const unsigned short* Vp = VT + ((size_t)b * NHEAD + h) * HD * SEQ;
    unsigned short* Pw = (unsigned short*)CMB + wave * 4096;
    const int sw8 = l16 & 7;  // swizzle key (row & 7)

#pragma unroll 1
    for (int half = 0; half < 2; ++half) {
        const int p = half ? y : (31 - y);  // heavy tile first
        const int row0 = p * 64;
        if (half) __syncthreads();  // previous combine's LDS reads done

        bf16x8 bQ[4][2];  // Q as B-operand: [q-frag][ks]
#pragma unroll
        for (int f = 0; f < 4; ++f)
#pragma unroll
            for (int ks = 0; ks < 2; ++ks)
                bQ[f][ks] = *(const bf16x8*)(Qp +
                    (size_t)(row0 + f * 16 + l16) * HD + ks * 32 + quad * 8);

        f32x4 o[4][4];    // O^T accumulators: [d-tile][q-frag]
        float ps[4] = {0.f, 0.f, 0.f, 0.f};
#pragma unroll
        for (int nt = 0; nt < 4; ++nt)
#pragma unroll
            for (int f = 0; f < 4; ++f)
                o[nt][f] = (f32x4){0.f, 0.f, 0.f, 0.f};

        for (int kt = wave; kt <= p; kt += 4) {
            bf16x8 aK[4][2], aV[4][2];
#pragma unroll
            for (int mt = 0; mt < 4; ++mt)
#pragma unroll
                for (int ks = 0; ks < 2; ++ks)
                    aK[mt][ks] = *(const bf16x8*)(Kp +
                        (size_t)(kt * 64 + mt * 16 + l16) * HD + ks * 32 + quad * 8);
#pragma unroll
            for (int nt = 0; nt < 4; ++nt)
#pragma unroll
                for (int ks = 0; ks < 2; ++ks)
                    aV[nt][ks] = *(const bf16x8*)(Vp +
                        (size_t)(nt * 16 + l16) * SEQ + kt * 64 + ks * 32 + quad * 8);

            // ---- S^T = K Q^T ----
            f32x4 sT[4][4];
            __builtin_amdgcn_s_setprio(1);
#pragma unroll
            for (int mt = 0; mt < 4; ++mt)
#pragma unroll
                for (int f = 0; f < 4; ++f) {
                    sT[mt][f] = __builtin_amdgcn_mfma_f32_16x16x32_bf16(
                        aK[mt][0], bQ[f][0], (f32x4){0.f, 0.f, 0.f, 0.f}, 0, 0, 0);
                    sT[mt][f] = __builtin_amdgcn_mfma_f32_16x16x32_bf16(
                        aK[mt][1], bQ[f][1], sT[mt][f], 0, 0, 0);
                }
            __builtin_amdgcn_s_setprio(0);

            // ---- exp2 + causal mask (diag tile only) + swizzled P write ----
            const bool diag = (kt == p);
#pragma unroll
            for (int mt = 0; mt < 4; ++mt)
#pragma unroll
                for (int f = 0; f < 4; ++f) {
                    float pv[4];
#pragma unroll
                    for (int reg = 0; reg < 4; ++reg)
                        pv[reg] = exp2f(sT[mt][f][reg]);
                    if (diag) {
                        const int kb = kt * 64 + mt * 16 + quad * 4;
                        const int qg = row0 + f * 16 + l16;
#pragma unroll
                        for (int reg = 0; reg < 4; ++reg)
                            pv[reg] = (kb + reg > qg) ? 0.f : pv[reg];
                    }
                    ps[f] += (pv[0] + pv[1]) + (pv[2] + pv[3]);
                    uint2 w;
                    w.x = pk2bf(pv[0], pv[1]);
                    w.y = pk2bf(pv[2], pv[3]);
                    const int gph = ((mt * 2 + (quad >> 1)) ^ sw8);
                    *(uint2*)&Pw[(f * 16 + l16) * 64 + gph * 8 + (quad & 1) * 4] = w;
                }

            // ---- P back in B-layout (wave-private; same-wave DS order) ----
            bf16x8 bP[4][2];
#pragma unroll
            for (int f = 0; f < 4; ++f)
#pragma unroll
                for (int ks = 0; ks < 2; ++ks)
                    bP[f][ks] = *(const bf16x8*)&Pw[(f * 16 + l16) * 64 +
                                                    ((ks * 4 + quad) ^ sw8) * 8];

            // ---- O^T += V^T P^T ----
            __builtin_amdgcn_s_setprio(1);
#pragma unroll
            for (int nt = 0; nt < 4; ++nt)
#pragma unroll
                for (int f = 0; f < 4; ++f) {
                    o[nt][f] = __builtin_amdgcn_mfma_f32_16x16x32_bf16(
                        aV[nt][0], bP[f][0], o[nt][f], 0, 0, 0);
                    o[nt][f] = __builtin_amdgcn_mfma_f32_16x16x32_bf16(
                        aV[nt][1], bP[f][1], o[nt][f], 0, 0, 0);
                }
            __builtin_amdgcn_s_setprio(0);
        }

#pragma unroll
        for (int f = 0; f < 4; ++f) {
            ps[f] += __shfl_xor(ps[f], 16);
            ps[f] += __shfl_xor(ps[f], 32);
        }

        // ---- cross-wave tree combine: {2,3} -> {0,1} -> 0 ----
        __syncthreads();  // all waves done with Pw (regions overlay it)
        if (wave >= 2) {
            float* Rg = CMB + (wave - 2) * 4352;
#pragma unroll
            for (int nt = 0; nt < 4; ++nt)
#pragma unroll
                for (int f = 0; f < 4; ++f)
                    *(f32x4*)&Rg[(f * 16 + l16) * 68 + nt * 16 + quad * 4] = o[nt][f];
            if (quad == 0)
#pragma unroll
                for (int f = 0; f < 4; ++f)
                    CMB[8704 + (wave - 2) * 64 + f * 16 + l16] = ps[f];
        }
        __syncthreads();
        if (wave < 2) {
            float* Rg = CMB + wave * 4352;
#pragma unroll
            for (int nt = 0; nt < 4; ++nt)
#pragma unroll
                for (int f = 0; f < 4; ++f)
                    o[nt][f] += *(const f32x4*)&Rg[(f * 16 + l16) * 68 + nt * 16 + quad * 4];
#pragma unroll
            for (int f = 0; f < 4; ++f)
                ps[f] += CMB[8704 + wave * 64 + f * 16 + l16];
        }
        __syncthreads();
        if (wave == 1) {
#pragma unroll
            for (int nt = 0; nt < 4; ++nt)
#pragma unroll
                for (int f = 0; f < 4; ++f)
                    *(f32x4*)&CMB[(f * 16 + l16) * 68 + nt * 16 + quad * 4] = o[nt][f];
            if (quad == 0)
#pragma unroll
                for (int f = 0; f < 4; ++f)
                    CMB[8704 + f * 16 + l16] = ps[f];
        }
        __syncthreads();
        if (wave == 0) {
#pragma unroll
            for (int nt = 0; nt < 4; ++nt)
#pragma unroll
                for (int f = 0; f < 4; ++f)
                    o[nt][f] += *(const f32x4*)&CMB[(f * 16 + l16) * 68 + nt * 16 + quad * 4];
            float inv[4];
#pragma unroll
            for (int f = 0; f < 4; ++f)
                inv[f] = 1.f / (ps[f] + CMB[8704 + f * 16 + l16]);
#pragma unroll
            for (int nt = 0; nt < 4; ++nt)
#pragma unroll
                for (int f = 0; f < 4; ++f) {
                    const int tok = row0 + f * 16 + l16;
                    const int col = h * HD + nt * 16 + quad * 4;
                    uint2 w;
                    w.x = pk2bf(o[nt][f][0] * inv[f], o[nt][f][1] * inv[f]);
                    w.y = pk2bf(o[nt][f][2] * inv[f], o[nt][f][3] * inv[f]);
                    *(uint2*)(ctx + ((size_t)b * SEQ + tok) * D_MODEL + col) = w;
                }
        }
    }
}

extern "C" void kernel_launch(void* const* d_in, const int* in_sizes, int n_in,
                              void* d_out, int out_size, void* d_ws, size_t ws_size,
                              hipStream_t stream) {
    const float* x  = (const float*)d_in[0];
    const float* Wq = (const float*)d_in[1];
    const float* Wk = (const float*)d_in[2];
    const float* Wv = (const float*)d_in[3];
    const float* Wo = (const float*)d_in[4];
    float* out = (float*)d_out;

    unsigned short* ws = (unsigned short*)d_ws;
    const size_t T = (size_t)MTOT * D_MODEL;  // 4,194,304 elements
    unsigned short* xb  = ws;                 // [4096,1024] bf16
    unsigned short* Wt  = ws + T;             // 4 x [1024,1024] bf16 (W^T)
    unsigned short* q   = ws + 2 * T;         // [B,H,N,64]  (pre-scaled)
    unsigned short* k   = ws + 3 * T;         // [B,H,N,64]
    unsigned short* vt  = ws + 4 * T;         // [B,H,64,N]
    unsigned short* ctx = ws + 5 * T;         // [4096,1024]

    prep<<<dim3(8192), dim3(256), 0, stream>>>(x, xb, Wq, Wk, Wv, Wo, Wt);

    qkv_mfma<<<dim3(192), dim3(512), 0, stream>>>(xb, Wt, q, k, vt);

    attn_mfma<<<dim3(NHEAD, 16, BATCH), dim3(256), 0, stream>>>(q, k, vt, ctx);

    gemm_out<<<dim3(8, 32), dim3(256), 0, stream>>>(ctx, Wt + 3 * (size_t)D_MODEL * D_MODEL, out);
}